// Round 11
// baseline (338.458 us; speedup 1.0000x reference)
//
#include <hip/hip_runtime.h>

#define N_NODES 100000
#define VROWS   200000          // virtual rows: [0,100000)=feat, [100000,200000)=adj
#define BSHIFT  8
#define BROWS   256             // rows per bucket
#define NBUCK   ((VROWS + BROWS - 1) / BROWS)   // 782
#define BINB    256             // blocks for binA/binB
#define NBAND   8               // src bands: col>>14 (adj cols <100000 -> bands 0..6)
#define SBINS   (BROWS * NBAND) // 2048 sort bins per bucket

static __device__ __forceinline__ unsigned short f2bf(float x) {
    unsigned u = __float_as_uint(x);
    return (unsigned short)((u + 0x7fffu + ((u >> 16) & 1u)) >> 16);
}
static __device__ __forceinline__ float bf_lo(unsigned u) { return __uint_as_float(u << 16); }
static __device__ __forceinline__ float bf_hi(unsigned u) { return __uint_as_float(u & 0xffff0000u); }

// nt load of a packed (col,val) element via long long (builtin rejects HIP vector types)
static __device__ __forceinline__ void nt_colval(const long long* p, int& c, float& v) {
    long long e = __builtin_nontemporal_load(p);
    c = (int)(e & 0x1ffffLL);
    v = __uint_as_float((unsigned)((unsigned long long)e >> 32));
}

// payload: lo = col(17b) | rowlocal(8b)<<17 ; hi = val bits
static __device__ __forceinline__ long long pack_cv(int col, int rl, float v) {
    unsigned lo = (unsigned)col | ((unsigned)rl << 17);
    return (long long)lo | ((long long)(unsigned)__float_as_uint(v) << 32);
}

// ---------------- CSR build: atomic-light two-pass multisplit ----------------

__global__ void zero_small_kernel(int* __restrict__ p, int n) {
    int i = blockIdx.x * blockDim.x + threadIdx.x;
    if (i < n) p[i] = 0;
}

// Pass A: per-block LDS histogram over buckets; ONE global atomic per (block,bucket).
__global__ __launch_bounds__(256) void binA_kernel(
        const int* __restrict__ f_rows, const int* __restrict__ a_rows,
        int* __restrict__ cur, int* __restrict__ pbb, int nnzf, int nedge) {
    __shared__ int hist[NBUCK];
    const int t = threadIdx.x;
    for (int b = t; b < NBUCK; b += 256) hist[b] = 0;
    __syncthreads();
    {
        const int per = (nnzf + BINB - 1) / BINB;
        const int beg = blockIdx.x * per;
        const int end = min(beg + per, nnzf);
        int i = beg + t;
        for (; i + 3 * 256 < end; i += 4 * 256) {
            int r0 = f_rows[i], r1 = f_rows[i + 256], r2 = f_rows[i + 512], r3 = f_rows[i + 768];
            atomicAdd(&hist[r0 >> BSHIFT], 1);
            atomicAdd(&hist[r1 >> BSHIFT], 1);
            atomicAdd(&hist[r2 >> BSHIFT], 1);
            atomicAdd(&hist[r3 >> BSHIFT], 1);
        }
        for (; i < end; i += 256) atomicAdd(&hist[f_rows[i] >> BSHIFT], 1);
    }
    {
        const int per = (nedge + BINB - 1) / BINB;
        const int beg = blockIdx.x * per;
        const int end = min(beg + per, nedge);
        int i = beg + t;
        for (; i + 3 * 256 < end; i += 4 * 256) {
            int r0 = a_rows[i] + N_NODES, r1 = a_rows[i + 256] + N_NODES;
            int r2 = a_rows[i + 512] + N_NODES, r3 = a_rows[i + 768] + N_NODES;
            atomicAdd(&hist[r0 >> BSHIFT], 1);
            atomicAdd(&hist[r1 >> BSHIFT], 1);
            atomicAdd(&hist[r2 >> BSHIFT], 1);
            atomicAdd(&hist[r3 >> BSHIFT], 1);
        }
        for (; i < end; i += 256) atomicAdd(&hist[(a_rows[i] + N_NODES) >> BSHIFT], 1);
    }
    __syncthreads();
    for (int b = t; b < NBUCK; b += 256) {
        int c = hist[b];
        pbb[blockIdx.x * NBUCK + b] = c ? atomicAdd(&cur[b], c) : 0;
    }
}

// Exclusive scan of 782 bucket counts -> bbase; rp[VROWS] = total.
__global__ void bucket_scan_kernel(const int* __restrict__ cur, int* __restrict__ bbase,
                                   int* __restrict__ rp) {
    __shared__ int sh[1024];
    const int t = threadIdx.x;
    int v = (t < NBUCK) ? cur[t] : 0;
    sh[t] = v;
    __syncthreads();
    for (int off = 1; off < 1024; off <<= 1) {
        int u = (t >= off) ? sh[t - off] : 0;
        __syncthreads();
        sh[t] += u;
        __syncthreads();
    }
    if (t < NBUCK) bbase[t] = sh[t] - v;
    if (t == NBUCK - 1) rp[VROWS] = sh[t];
}

// Pass B: replay chunk; place payloads at bbase[b] + pbb[block][b] + ldscursor.
__global__ __launch_bounds__(256) void binB_kernel(
        const int* __restrict__ f_rows, const int* __restrict__ f_cols, const float* __restrict__ f_vals,
        const int* __restrict__ a_rows, const int* __restrict__ a_cols, const float* __restrict__ a_vals,
        const int* __restrict__ bbase, const int* __restrict__ pbb,
        long long* __restrict__ staging, int nnzf, int nedge) {
    __shared__ int curs[NBUCK];
    const int t = threadIdx.x;
    for (int b = t; b < NBUCK; b += 256) curs[b] = bbase[b] + pbb[blockIdx.x * NBUCK + b];
    __syncthreads();
    {
        const int per = (nnzf + BINB - 1) / BINB;
        const int beg = blockIdx.x * per;
        const int end = min(beg + per, nnzf);
        for (int i = beg + t; i < end; i += 256) {
            const int   r = f_rows[i];
            const int   c = f_cols[i];
            const float v = f_vals[i];
            const int p = atomicAdd(&curs[r >> BSHIFT], 1);
            staging[p] = pack_cv(c, r & (BROWS - 1), v);
        }
    }
    {
        const int per = (nedge + BINB - 1) / BINB;
        const int beg = blockIdx.x * per;
        const int end = min(beg + per, nedge);
        for (int i = beg + t; i < end; i += 256) {
            const int   r = a_rows[i] + N_NODES;
            const int   c = a_cols[i];
            const float v = a_vals[i];
            const int p = atomicAdd(&curs[r >> BSHIFT], 1);
            staging[p] = pack_cv(c, r & (BROWS - 1), v);
        }
    }
}

// Per-bucket sort by (rowlocal, src_band): 2048 LDS bins. Band-ordering within
// each row makes the whole chip's gather front sweep src space band-by-band,
// so the instantaneous working set fits each XCD's 4MB L2 (R10: 215MB L2-miss
// traffic on a 25.6MB buffer). Thread t owns exactly row t's 8 bins.
__global__ __launch_bounds__(256) void sort_kernel(
        const int* __restrict__ cur, const int* __restrict__ bbase,
        const long long* __restrict__ staging, long long* __restrict__ colval,
        int* __restrict__ rp) {
    const int b = blockIdx.x;
    const int t = threadIdx.x;
    __shared__ int cnt[SBINS];
    __shared__ int tsum[256];
    const int n = cur[b];
    const int base = bbase[b];
    for (int k = t; k < SBINS; k += 256) cnt[k] = 0;
    __syncthreads();
    const long long* seg = staging + base;
    for (int j = t; j < n; j += 256) {
        unsigned lo = (unsigned)(seg[j] & 0xffffffffLL);
        const int rl = (lo >> 17) & (BROWS - 1);
        const int band = (int)((lo & 0x1ffffu) >> 14);
        atomicAdd(&cnt[rl * NBAND + band], 1);
    }
    __syncthreads();
    // scan 2048 bins: thread t serially scans its row's 8 bins, then block-scan of totals
    int loc[NBAND];
    int s = 0;
    #pragma unroll
    for (int k = 0; k < NBAND; ++k) { loc[k] = s; s += cnt[t * NBAND + k]; }
    tsum[t] = s;
    __syncthreads();
    for (int o = 1; o < 256; o <<= 1) {
        int u = (t >= o) ? tsum[t - o] : 0;
        __syncthreads();
        tsum[t] += u;
        __syncthreads();
    }
    const int texcl = (t == 0) ? 0 : tsum[t - 1];   // start of row t within bucket
    const int row = (b << BSHIFT) + t;
    if (row < VROWS) rp[row] = base + texcl;
    #pragma unroll
    for (int k = 0; k < NBAND; ++k) cnt[t * NBAND + k] = base + texcl + loc[k];  // absolute cursors
    __syncthreads();
    // place
    for (int j = t; j < n; j += 256) {
        long long e = seg[j];
        unsigned lo = (unsigned)(e & 0xffffffffLL);
        const int rl = (lo >> 17) & (BROWS - 1);
        const int band = (int)((lo & 0x1ffffu) >> 14);
        const int p = atomicAdd(&cnt[rl * NBAND + band], 1);
        colval[p] = (long long)(lo & 0x1ffffu) | (e & 0xffffffff00000000LL);
    }
}

// ---------------- SpMM feat: one row per 32-lane half-wave ----------------

__global__ __launch_bounds__(256) void spmm_feat_kernel(
        const int* __restrict__ row_ptr, const long long* __restrict__ colval,
        const float* __restrict__ W, const float* __restrict__ bias,
        unsigned short* __restrict__ base_bf, int n) {
    const int wave = (blockIdx.x * blockDim.x + threadIdx.x) >> 6;
    const int lane = threadIdx.x & 63;
    const int h = lane >> 5;
    const int s = lane & 31;
    const int r = wave * 2 + h;
    const float4* __restrict__ W4 = (const float4*)W;
    float4 a0 = make_float4(0.f, 0.f, 0.f, 0.f), a1 = a0;
    int i = 0, end = 0;
    if (r < n) { i = row_ptr[r]; end = row_ptr[r + 1]; }
    for (; i + 1 < end; i += 2) {
        int c0, c1; float v0, v1;
        nt_colval(colval + i,     c0, v0);
        nt_colval(colval + i + 1, c1, v1);
        const float4 w0 = W4[c0 * 32 + s];
        const float4 w1 = W4[c1 * 32 + s];
        a0.x += v0 * w0.x; a0.y += v0 * w0.y; a0.z += v0 * w0.z; a0.w += v0 * w0.w;
        a1.x += v1 * w1.x; a1.y += v1 * w1.y; a1.z += v1 * w1.z; a1.w += v1 * w1.w;
    }
    if (i < end) {
        int c; float v;
        nt_colval(colval + i, c, v);
        const float4 w = W4[c * 32 + s];
        a0.x += v * w.x; a0.y += v * w.y; a0.z += v * w.z; a0.w += v * w.w;
    }
    if (r < n) {
        const float4 b = ((const float4*)bias)[s];
        ushort4 o;
        o.x = f2bf(fmaxf(a0.x + a1.x + b.x, 0.f));
        o.y = f2bf(fmaxf(a0.y + a1.y + b.y, 0.f));
        o.z = f2bf(fmaxf(a0.z + a1.z + b.z, 0.f));
        o.w = f2bf(fmaxf(a0.w + a1.w + b.w, 0.f));
        ((ushort4*)(base_bf + (size_t)r * 128))[s] = o;
    }
}

// ---------------- adjacency pass: bf16 in / bf16 out, row-per-half ----------------

__global__ __launch_bounds__(256) void spmm_adj_bf_bf_kernel(
        const int* __restrict__ row_ptr, const long long* __restrict__ colval,
        const uint2* __restrict__ src, unsigned short* __restrict__ dst, int n) {
    const int wave = (blockIdx.x * blockDim.x + threadIdx.x) >> 6;
    const int lane = threadIdx.x & 63;
    const int h = lane >> 5;
    const int s = lane & 31;
    const int r = wave * 2 + h;
    float4 a0 = make_float4(0.f, 0.f, 0.f, 0.f), a1 = a0;
    int i = 0, end = 0;
    if (r < n) { i = row_ptr[r]; end = row_ptr[r + 1]; }
    for (; i + 1 < end; i += 2) {
        int c0, c1; float v0, v1;
        nt_colval(colval + i,     c0, v0);
        nt_colval(colval + i + 1, c1, v1);
        const uint2 u0 = src[c0 * 32 + s];
        const uint2 u1 = src[c1 * 32 + s];
        a0.x += v0 * bf_lo(u0.x); a0.y += v0 * bf_hi(u0.x);
        a0.z += v0 * bf_lo(u0.y); a0.w += v0 * bf_hi(u0.y);
        a1.x += v1 * bf_lo(u1.x); a1.y += v1 * bf_hi(u1.x);
        a1.z += v1 * bf_lo(u1.y); a1.w += v1 * bf_hi(u1.y);
    }
    if (i < end) {
        int c; float v;
        nt_colval(colval + i, c, v);
        const uint2 u = src[c * 32 + s];
        a0.x += v * bf_lo(u.x); a0.y += v * bf_hi(u.x);
        a0.z += v * bf_lo(u.y); a0.w += v * bf_hi(u.y);
    }
    if (r < n) {
        ushort4 o;
        o.x = f2bf(a0.x + a1.x); o.y = f2bf(a0.y + a1.y);
        o.z = f2bf(a0.z + a1.z); o.w = f2bf(a0.w + a1.w);
        ((ushort4*)(dst + (size_t)r * 128))[s] = o;
    }
}

// ---------------- adjacency pass: bf16 in / f32 out, row-per-half ----------------

__global__ __launch_bounds__(256) void spmm_adj_bf_f32_kernel(
        const int* __restrict__ row_ptr, const long long* __restrict__ colval,
        const uint2* __restrict__ src, float* __restrict__ dst, int n) {
    const int wave = (blockIdx.x * blockDim.x + threadIdx.x) >> 6;
    const int lane = threadIdx.x & 63;
    const int h = lane >> 5;
    const int s = lane & 31;
    const int r = wave * 2 + h;
    float4 a0 = make_float4(0.f, 0.f, 0.f, 0.f), a1 = a0;
    int i = 0, end = 0;
    if (r < n) { i = row_ptr[r]; end = row_ptr[r + 1]; }
    for (; i + 1 < end; i += 2) {
        int c0, c1; float v0, v1;
        nt_colval(colval + i,     c0, v0);
        nt_colval(colval + i + 1, c1, v1);
        const uint2 u0 = src[c0 * 32 + s];
        const uint2 u1 = src[c1 * 32 + s];
        a0.x += v0 * bf_lo(u0.x); a0.y += v0 * bf_hi(u0.x);
        a0.z += v0 * bf_lo(u0.y); a0.w += v0 * bf_hi(u0.y);
        a1.x += v1 * bf_lo(u1.x); a1.y += v1 * bf_hi(u1.x);
        a1.z += v1 * bf_lo(u1.y); a1.w += v1 * bf_hi(u1.y);
    }
    if (i < end) {
        int c; float v;
        nt_colval(colval + i, c, v);
        const uint2 u = src[c * 32 + s];
        a0.x += v * bf_lo(u.x); a0.y += v * bf_hi(u.x);
        a0.z += v * bf_lo(u.y); a0.w += v * bf_hi(u.y);
    }
    if (r < n) {
        float4 acc;
        acc.x = a0.x + a1.x; acc.y = a0.y + a1.y;
        acc.z = a0.z + a1.z; acc.w = a0.w + a1.w;
        ((float4*)(dst + (size_t)r * 128))[s] = acc;
    }
}

// ---------------- launch ----------------

extern "C" void kernel_launch(void* const* d_in, const int* in_sizes, int n_in,
                              void* d_out, int out_size, void* d_ws, size_t ws_size,
                              hipStream_t stream) {
    const int*   fi   = (const int*)d_in[0];     // feat_indices [2, nnzf]
    const float* fv   = (const float*)d_in[1];   // feat_values  [nnzf]
    const int*   ai   = (const int*)d_in[2];     // adj_indices  [2, nedge]
    const float* av   = (const float*)d_in[3];   // adj_values   [nedge]
    const float* W    = (const float*)d_in[4];   // weight [512,128]
    const float* bias = (const float*)d_in[5];   // bias [1,128]
    float* out = (float*)d_out;

    const int nnzf  = in_sizes[1];
    const int nedge = in_sizes[3];
    const int ntot  = nnzf + nedge;
    const int* f_rows = fi;
    const int* f_cols = fi + nnzf;
    const int* a_rows = ai;
    const int* a_cols = ai + nedge;

    // bump-allocate workspace (256B aligned)
    char* wp = (char*)d_ws;
    auto balloc = [&](size_t bytes) -> char* {
        char* p = wp;
        wp += (bytes + 255) & ~(size_t)255;
        return p;
    };
    // staging (28.8MB) dead after sort; base_bf (25.6MB) overlays it.
    long long* staging = (long long*)balloc(8ull * (size_t)ntot);
    unsigned short* base_bf = (unsigned short*)staging;
    unsigned short* t1 = (unsigned short*)balloc(2ull * N_NODES * 128);
    long long* colval = (long long*)balloc(8ull * (size_t)ntot);
    int* rp    = (int*)balloc(4ull * (VROWS + 1));
    int* cur   = (int*)balloc(4ull * NBUCK);
    int* bbase = (int*)balloc(4ull * NBUCK);
    int* pbb   = (int*)balloc(4ull * BINB * NBUCK);

    const int nwaves = (N_NODES + 1) / 2;          // 2 rows per wave
    const int RW = (nwaves + 3) / 4;               // 4 waves per 256-thread block

    // ---- CSR build: histogram -> scan -> place -> per-bucket (row,band) sort ----
    zero_small_kernel<<<(NBUCK + 255) / 256, 256, 0, stream>>>(cur, NBUCK);
    binA_kernel<<<BINB, 256, 0, stream>>>(f_rows, a_rows, cur, pbb, nnzf, nedge);
    bucket_scan_kernel<<<1, 1024, 0, stream>>>(cur, bbase, rp);
    binB_kernel<<<BINB, 256, 0, stream>>>(f_rows, f_cols, fv, a_rows, a_cols, av,
                                          bbase, pbb, staging, nnzf, nedge);
    sort_kernel<<<NBUCK, 256, 0, stream>>>(cur, bbase, staging, colval, rp);

    // ---- compute: feat -> base_bf(bf16), adj -> t1(bf16), adj -> out(f32) ----
    spmm_feat_kernel<<<RW, 256, 0, stream>>>(rp, colval, W, bias, base_bf, N_NODES);
    spmm_adj_bf_bf_kernel<<<RW, 256, 0, stream>>>(rp + N_NODES, colval,
                                                  (const uint2*)base_bf, t1, N_NODES);
    spmm_adj_bf_f32_kernel<<<RW, 256, 0, stream>>>(rp + N_NODES, colval,
                                                   (const uint2*)t1, out, N_NODES);
}